// Round 12
// baseline (556.856 us; speedup 1.0000x reference)
//
#include <hip/hip_runtime.h>
#include <hip/hip_bf16.h>

// Problem constants (from reference setup_inputs)
#define F_SIZE 1024
#define E_DIM  128
#define N_D    6000
#define N_SE   1000
#define N_TOT  7000
#define M_TPL  300000
#define LAMB   1e-6f
#define KPAD   7168   // 56*128: padded K extent (xT cols, Atl k)
#define NXT    110    // x-tiles (7040 rows padded)
#define KTT    56     // k-tiles of 128 in KPAD
#define SPL_AX  12    // split-K for A@x: 110 * 12 = 1320 blocks (~5.2/CU)
#define SPL_MLP 8     // split-K for MLP1: 94 * 8 = 752 blocks
#define SVPAD  7168   // svec row stride

typedef __bf16 bf16x8 __attribute__((ext_vector_type(8)));
typedef float  f32x4  __attribute__((ext_vector_type(4)));
typedef unsigned short u16;

__device__ __forceinline__ float hshrink(float v) {
    return fabsf(v) > LAMB ? v : 0.0f;
}

// RNE float -> bf16 bits (inputs are finite; no NaN handling needed)
__device__ __forceinline__ u16 f2bf(float f) {
    unsigned int u = __builtin_bit_cast(unsigned int, f);
    unsigned int r = u + 0x7fffu + ((u >> 16) & 1u);
    return (u16)(r >> 16);
}

// Async global->LDS DMA, 16B per lane. LDS dest wave-uniform + lane*16.
__device__ __forceinline__ void gl_lds16(const void* g, void* l) {
    __builtin_amdgcn_global_load_lds(
        (__attribute__((address_space(1))) void*)(void*)(g),
        (__attribute__((address_space(3))) void*)(l), 16, 0, 0);
}

// ---------------------------------------------------------------------------
// Repack A (fp32 [7000][7000], row-major) into k-tiled swizzled bf16:
//   Atl[x][kt][rl][pos],  x=row/64, rl=row%64, kt=k/128,
//   pos = (chunk ^ (rl&15))*8 + (k&7),  chunk=(k%128)/8.
// READ side is perfectly linear (one row per block = 28 KB sequential).
// The XOR bakes the GEMM's LDS bank-swizzle into memory (rule-21: linear
// LDS dest, pre-permuted source). Rows/cols >= 7000 zero-filled.
// After this, each GEMM block's A-read is ONE contiguous run -> DRAM-linear.
// ---------------------------------------------------------------------------
__global__ __launch_bounds__(256) void repack_a(const float* __restrict__ A,
                                                u16* __restrict__ Atl) {
    const int r  = blockIdx.x;            // 0..7039
    const int x  = r >> 6;
    const int rl = r & 63;
    const int sw = rl & 15;
    const float* sp = A + (size_t)r * N_TOT;
    u16* dp = Atl + (size_t)x * (KTT * 64 * 128);
    for (int cg = threadIdx.x; cg < KPAD / 8; cg += 256) {   // 896 chunks
        const int k0 = cg * 8;
        const int kt = cg >> 4;
        const int c  = cg & 15;
        u16 us[8];
        if (r < N_TOT && k0 + 8 <= N_TOT) {
            float4 v0 = *(const float4*)(sp + k0);
            float4 v1 = *(const float4*)(sp + k0 + 4);
            us[0] = f2bf(v0.x); us[1] = f2bf(v0.y);
            us[2] = f2bf(v0.z); us[3] = f2bf(v0.w);
            us[4] = f2bf(v1.x); us[5] = f2bf(v1.y);
            us[6] = f2bf(v1.z); us[7] = f2bf(v1.w);
        } else if (r < N_TOT && k0 < N_TOT) {
#pragma unroll
            for (int i = 0; i < 8; i++)
                us[i] = (k0 + i < N_TOT) ? f2bf(sp[k0 + i]) : (u16)0;
        } else {
#pragma unroll
            for (int i = 0; i < 8; i++) us[i] = 0;
        }
        *(uint4*)(dp + (size_t)kt * 8192 + rl * 128 + ((c ^ sw) * 8)) =
            *(uint4*)us;
    }
}

// ---------------------------------------------------------------------------
// A@x GEMM over the tiled layout: block (x, sp) streams Atl[x][kt0..kt1)
// -- a CONTIGUOUS (kt1-kt0)*16 KB run (the DRAM-linear fix).
// BK=128, BM=64, BN=128. 2-deep LDS dbuf, counted vmcnt (r9 skeleton).
// B fragments are pre-loaded to VGPRs BEFORE the stage-DMAs each iter so the
// in-order vmcnt(4) drains {old DMAs + B} and leaves the new 4 DMAs in
// flight across compute+barriers.
// ---------------------------------------------------------------------------
__global__ __launch_bounds__(256) void gemm_tiled(const u16* __restrict__ Atl,
                                                  const u16* __restrict__ BT,
                                                  float* __restrict__ Cpart,
                                                  int M) {
    __shared__ u16 As[2][64 * 128];   // 2 x 16 KB
    const int tid  = threadIdx.x;
    const int lane = tid & 63;
    const int w    = tid >> 6;
    const int fm   = lane & 15;
    const int quad = lane >> 4;
    const int wm   = (w & 1) * 32;
    const int wn   = (w >> 1) * 64;
    const int xt   = blockIdx.x;
    const int row0 = xt * 64;
    const int sp = blockIdx.y, nsp = gridDim.y;
    const int kt0 = sp * KTT / nsp;
    const int kt1 = (sp + 1) * KTT / nsp;

    const u16* tb = Atl + (size_t)xt * (KTT * 64 * 128);
    const int sOff = w * 2048 + lane * 8;     // stage src/dst base (elems)
    int bOff[4];
#pragma unroll
    for (int ni = 0; ni < 4; ni++)
        bOff[ni] = (wn + ni * 16 + fm) * KPAD + quad * 8;

    const f32x4 zero = {0.f, 0.f, 0.f, 0.f};
    f32x4 acc[2][4];
#pragma unroll
    for (int i = 0; i < 2; i++)
#pragma unroll
        for (int j = 0; j < 4; j++) acc[i][j] = zero;

    bf16x8 bfr[4][4];

#define STAGE_T(buf, kt)                                                      \
    {                                                                         \
        const u16* s = tb + (size_t)(kt) * 8192 + sOff;                       \
        _Pragma("unroll") for (int j = 0; j < 4; j++)                         \
            gl_lds16(s + j * 512, &As[buf][w * 2048 + j * 512]);              \
    }

#define BLOAD_T(kt)                                                           \
    {                                                                         \
        const int k0b = (kt) * 128;                                           \
        _Pragma("unroll") for (int ks = 0; ks < 4; ks++)                      \
            _Pragma("unroll") for (int ni = 0; ni < 4; ni++)                  \
                bfr[ks][ni] = *(const bf16x8*)(BT + bOff[ni] + k0b + ks * 32);\
    }

#define COMPUTE_T(buf)                                                        \
    {                                                                         \
        _Pragma("unroll") for (int ks = 0; ks < 4; ks++)                      \
            _Pragma("unroll") for (int mi = 0; mi < 2; mi++) {                \
                int rl = wm + mi * 16 + fm;                                   \
                bf16x8 af = *(const bf16x8*)&As[buf][rl * 128 +               \
                                (((ks * 4 + quad) ^ (rl & 15)) * 8)];         \
                _Pragma("unroll") for (int ni = 0; ni < 4; ni++)              \
                    acc[mi][ni] = __builtin_amdgcn_mfma_f32_16x16x32_bf16(    \
                        af, bfr[ks][ni], acc[mi][ni], 0, 0, 0);               \
            }                                                                 \
    }

    STAGE_T(0, kt0);
    for (int t = kt0; t < kt1; t++) {
        const int cur = (t - kt0) & 1;
        BLOAD_T(t);                         // B older than next stage's DMAs
        if (t + 1 < kt1) {
            STAGE_T(cur ^ 1, t + 1);        // issue next tile's 4 DMAs
            // drains {prev stage's DMAs + B loads}, leaves new 4 in flight
            asm volatile("s_waitcnt vmcnt(4)" ::: "memory");
        } else {
            asm volatile("s_waitcnt vmcnt(0)" ::: "memory");
        }
        __builtin_amdgcn_s_barrier();       // tile t landed for all waves
        COMPUTE_T(cur);
        __builtin_amdgcn_s_barrier();       // all done reading buf
    }
#undef STAGE_T
#undef BLOAD_T
#undef COMPUTE_T

    float* op = Cpart + (size_t)sp * M * E_DIM;
#pragma unroll
    for (int mi = 0; mi < 2; mi++) {
#pragma unroll
        for (int rr = 0; rr < 4; rr++) {
            int row = row0 + wm + mi * 16 + quad * 4 + rr;
            if (row < M) {
#pragma unroll
                for (int ni = 0; ni < 4; ni++)
                    op[(size_t)row * E_DIM + wn + ni * 16 + fm] = acc[mi][ni][rr];
            }
        }
    }
}

// ---------------------------------------------------------------------------
// r9's proven MLP1 GEMM: fp32 A staged, BK=32, 2-deep dbuf, vmcnt(4).
// (K=1024 -> all tiles full; tail path never taken here.)
// ---------------------------------------------------------------------------
__global__ __launch_bounds__(256) void gemm_dma(const float* __restrict__ A, int lda,
                                                const u16* __restrict__ BT, int ldbt,
                                                float* __restrict__ Cpart,
                                                int M, int K) {
    __shared__ float As[2][64 * 32];
    __shared__ u16   Bs[2][128 * 32];
    const int tid  = threadIdx.x;
    const int lane = tid & 63;
    const int w    = tid >> 6;
    const int fm   = lane & 15;
    const int quad = lane >> 4;
    const int wm   = (w & 1) * 32;
    const int wn   = (w >> 1) * 64;
    const int row0 = blockIdx.x * 64;
    const int sp = blockIdx.y, nsp = gridDim.y;
    const int KT  = (K + 31) / 32;
    const int kt0 = sp * KT / nsp;
    const int kt1 = (sp + 1) * KT / nsp;
    const int ktFall = K >> 5;
    const int ktF = kt1 < ktFall ? kt1 : ktFall;

    int aLoc[2], aQ[2];
    const float* aG[2];
#pragma unroll
    for (int j = 0; j < 2; j++) {
        int r = w * 16 + j * 8 + (lane >> 3);
        aLoc[j] = r;
        int grow = row0 + r; if (grow > M - 1) grow = M - 1;
        aQ[j] = (lane & 7) ^ (r & 7);
        aG[j] = A + (size_t)grow * lda + aQ[j] * 4;
    }
    const u16* bG[2];
#pragma unroll
    for (int j = 0; j < 2; j++) {
        int n = w * 32 + j * 16 + (lane >> 2);
        int q = (lane & 3) ^ ((n >> 1) & 3);
        bG[j] = BT + (size_t)n * ldbt + q * 8;
    }

    const f32x4 zero = {0.f, 0.f, 0.f, 0.f};
    f32x4 acc[2][4];
#pragma unroll
    for (int i = 0; i < 2; i++)
#pragma unroll
        for (int j = 0; j < 4; j++) acc[i][j] = zero;

#define STAGE_T(buf, kt)                                                      \
    {                                                                         \
        const int k0s = (kt) * 32;                                            \
        _Pragma("unroll") for (int j = 0; j < 2; j++)                         \
            gl_lds16(aG[j] + k0s, &As[buf][(w * 16 + j * 8) * 32]);           \
        _Pragma("unroll") for (int j = 0; j < 2; j++)                         \
            gl_lds16(bG[j] + k0s, &Bs[buf][(w * 32 + j * 16) * 32]);          \
    }

#define COMPUTE_T(buf)                                                        \
    {                                                                         \
        bf16x8 bfr[4];                                                        \
        _Pragma("unroll") for (int ni = 0; ni < 4; ni++) {                    \
            int n = wn + ni * 16 + fm;                                        \
            bfr[ni] = *(const bf16x8*)&Bs[buf][n * 32 +                       \
                                              (quad ^ ((n >> 1) & 3)) * 8];   \
        }                                                                     \
        _Pragma("unroll") for (int mi = 0; mi < 2; mi++) {                    \
            int r = wm + mi * 16 + fm;                                        \
            int s = r & 7;                                                    \
            f32x4 f0 = *(const f32x4*)&As[buf][r * 32 + ((quad * 2) ^ s) * 4];\
            f32x4 f1 = *(const f32x4*)&As[buf][r * 32 +                       \
                                              ((quad * 2 + 1) ^ s) * 4];      \
            u16 us[8];                                                        \
            us[0] = f2bf(f0[0]); us[1] = f2bf(f0[1]);                         \
            us[2] = f2bf(f0[2]); us[3] = f2bf(f0[3]);                         \
            us[4] = f2bf(f1[0]); us[5] = f2bf(f1[1]);                         \
            us[6] = f2bf(f1[2]); us[7] = f2bf(f1[3]);                         \
            bf16x8 af = *(bf16x8*)us;                                         \
            _Pragma("unroll") for (int ni = 0; ni < 4; ni++)                  \
                acc[mi][ni] = __builtin_amdgcn_mfma_f32_16x16x32_bf16(        \
                    af, bfr[ni], acc[mi][ni], 0, 0, 0);                       \
        }                                                                     \
    }

    if (ktF > kt0) {
        STAGE_T(0, kt0);
        for (int t = kt0; t < ktF; t++) {
            const int cur = (t - kt0) & 1;
            if (t + 1 < ktF) {
                STAGE_T(cur ^ 1, t + 1);
                asm volatile("s_waitcnt vmcnt(4)" ::: "memory");
            } else {
                asm volatile("s_waitcnt vmcnt(0)" ::: "memory");
            }
            __builtin_amdgcn_s_barrier();
            COMPUTE_T(cur);
            __builtin_amdgcn_s_barrier();
        }
    }
    for (int kt = ktF; kt < kt1; kt++) {
        const int k0 = kt * 32;
        __syncthreads();
#pragma unroll
        for (int j = 0; j < 2; j++) {
            float4 v = make_float4(0.f, 0.f, 0.f, 0.f);
            if (k0 + aQ[j] * 4 + 4 <= K) v = *(const float4*)(aG[j] + k0);
            *(float4*)&As[0][aLoc[j] * 32 + (lane & 7) * 4] = v;
        }
#pragma unroll
        for (int j = 0; j < 2; j++)
            gl_lds16(bG[j] + k0, &Bs[0][(w * 32 + j * 16) * 32]);
        __syncthreads();
        COMPUTE_T(0);
    }
#undef STAGE_T
#undef COMPUTE_T

    float* op = Cpart + (size_t)sp * M * E_DIM;
#pragma unroll
    for (int mi = 0; mi < 2; mi++) {
#pragma unroll
        for (int rr = 0; rr < 4; rr++) {
            int row = row0 + wm + mi * 16 + quad * 4 + rr;
            if (row < M) {
#pragma unroll
                for (int ni = 0; ni < 4; ni++)
                    op[(size_t)row * E_DIM + wn + ni * 16 + fm] = acc[mi][ni][rr];
            }
        }
    }
}

// ---------------------------------------------------------------------------
// Small GEMM (K=128), BM=16: fuses the split-K reduction of its fp32 A input.
// ---------------------------------------------------------------------------
__global__ __launch_bounds__(256) void gemm_small2(const float* __restrict__ parts,
                                                   int nparts, size_t partStride,
                                                   const float* __restrict__ preBias,
                                                   const float* __restrict__ W,
                                                   const float* __restrict__ bias,
                                                   float* __restrict__ outp,
                                                   int Mrows, int act) {
    __shared__ float Asum[16][132];
    const int tid = threadIdx.x;
    const int row0 = blockIdx.x * 16;
    const int r  = tid >> 4;
    const int kc = (tid & 15) * 8;
    const int grow = row0 + r;

    float4 s0 = make_float4(0.f, 0.f, 0.f, 0.f);
    float4 s1 = make_float4(0.f, 0.f, 0.f, 0.f);
    if (grow < Mrows) {
        for (int s = 0; s < nparts; s++) {
            const float* p = parts + (size_t)s * partStride + (size_t)grow * 128 + kc;
            float4 q0 = *(const float4*)p;
            float4 q1 = *(const float4*)(p + 4);
            s0.x += q0.x; s0.y += q0.y; s0.z += q0.z; s0.w += q0.w;
            s1.x += q1.x; s1.y += q1.y; s1.z += q1.z; s1.w += q1.w;
        }
        if (preBias != nullptr) {
            float4 pb0 = *(const float4*)(preBias + kc);
            float4 pb1 = *(const float4*)(preBias + kc + 4);
            s0.x = fmaxf(s0.x + pb0.x, 0.f); s0.y = fmaxf(s0.y + pb0.y, 0.f);
            s0.z = fmaxf(s0.z + pb0.z, 0.f); s0.w = fmaxf(s0.w + pb0.w, 0.f);
            s1.x = fmaxf(s1.x + pb1.x, 0.f); s1.y = fmaxf(s1.y + pb1.y, 0.f);
            s1.z = fmaxf(s1.z + pb1.z, 0.f); s1.w = fmaxf(s1.w + pb1.w, 0.f);
        }
    }
    *(float4*)&Asum[r][kc]     = s0;
    *(float4*)&Asum[r][kc + 4] = s1;
    __syncthreads();

    float acc[8];
#pragma unroll
    for (int j = 0; j < 8; j++) acc[j] = 0.f;
    const float* wp = W + kc;
#pragma unroll 4
    for (int k = 0; k < 128; k++) {
        float a = Asum[r][k];
        float4 w0 = *(const float4*)(wp + (size_t)k * 128);
        float4 w1 = *(const float4*)(wp + (size_t)k * 128 + 4);
        acc[0] += a * w0.x; acc[1] += a * w0.y;
        acc[2] += a * w0.z; acc[3] += a * w0.w;
        acc[4] += a * w1.x; acc[5] += a * w1.y;
        acc[6] += a * w1.z; acc[7] += a * w1.w;
    }
    if (grow < Mrows) {
        float4 bv0 = *(const float4*)(bias + kc);
        float4 bv1 = *(const float4*)(bias + kc + 4);
        float v[8];
        v[0] = acc[0] + bv0.x; v[1] = acc[1] + bv0.y;
        v[2] = acc[2] + bv0.z; v[3] = acc[3] + bv0.w;
        v[4] = acc[4] + bv1.x; v[5] = acc[5] + bv1.y;
        v[6] = acc[6] + bv1.z; v[7] = acc[7] + bv1.w;
#pragma unroll
        for (int j = 0; j < 8; j++)
            v[j] = (act == 0) ? fmaxf(v[j], 0.f) : hshrink(v[j]);
        float* op = outp + (size_t)grow * 128 + kc;
        *(float4*)op       = make_float4(v[0], v[1], v[2], v[3]);
        *(float4*)(op + 4) = make_float4(v[4], v[5], v[6], v[7]);
    }
}

// ---------------------------------------------------------------------------
__global__ void emb_copy(const float* __restrict__ embSe, float* __restrict__ x) {
    int i = blockIdx.x * blockDim.x + threadIdx.x;
    if (i < N_SE * E_DIM / 4)
        ((float4*)(x + (size_t)N_D * E_DIM))[i] = ((const float4*)embSe)[i];
}

// ---------------------------------------------------------------------------
// src [nrows][128] fp32 -> dst [128][kpad] bf16 (cols >= nrows zero-filled)
// grid: (kpad/64, 2)
// ---------------------------------------------------------------------------
__global__ __launch_bounds__(256) void transpose_bf16(const float* __restrict__ src,
                                                      u16* __restrict__ dst,
                                                      int nrows, int kpad) {
    __shared__ float t[64][65];
    const int r0 = blockIdx.x * 64;
    const int c0 = blockIdx.y * 64;
    const int tid = threadIdx.x;
    {
        const int i  = tid >> 4;
        const int cq = (tid & 15) * 4;
#pragma unroll
        for (int j = 0; j < 4; j++) {
            int r = r0 + i + j * 16;
            float4 v = make_float4(0.f, 0.f, 0.f, 0.f);
            if (r < nrows) v = *(const float4*)(src + (size_t)r * E_DIM + c0 + cq);
            t[i + j * 16][cq + 0] = v.x;
            t[i + j * 16][cq + 1] = v.y;
            t[i + j * 16][cq + 2] = v.z;
            t[i + j * 16][cq + 3] = v.w;
        }
    }
    __syncthreads();
    {
        const int ci = tid >> 2;
        const int rq = (tid & 3) * 16;
        u16 us[16];
#pragma unroll
        for (int j = 0; j < 16; j++) us[j] = f2bf(t[rq + j][ci]);
        u16* dp = dst + (size_t)(c0 + ci) * kpad + r0 + rq;
        *(uint4*)dp       = *(uint4*)&us[0];
        *(uint4*)(dp + 8) = *(uint4*)&us[8];
    }
}

// ---------------------------------------------------------------------------
// Head algebra (inner hardshrink ~= identity at lambda=1e-6):
//   out[m] = HS( s0[d1] + s1[d2] + s2[se] + c0 )
//   s_j[r] = rsd[r] * (x[r] . wv_j),  wv_j = Wp1[j*128:(j+1)*128] @ Wp2
// ---------------------------------------------------------------------------
__global__ __launch_bounds__(256) void head_wvec(const float* __restrict__ Wp1,
                                                 const float* __restrict__ Wp2,
                                                 const float* __restrict__ bp1,
                                                 const float* __restrict__ bp2,
                                                 float* __restrict__ wv) {
    const int tid = threadIdx.x;
#pragma unroll
    for (int rr = 0; rr < 2; rr++) {
        int row = tid + rr * 256;
        if (row < 384) {
            const float* wp = Wp1 + (size_t)row * 128;
            float s = 0.f;
            for (int n = 0; n < 128; n += 4) {
                float4 a = *(const float4*)(wp + n);
                float4 b = *(const float4*)(Wp2 + n);
                s += a.x * b.x + a.y * b.y + a.z * b.z + a.w * b.w;
            }
            wv[row] = s;
        }
    }
    if (tid == 0) {
        float s = 0.f;
        for (int n = 0; n < 128; n++) s += bp1[n] * Wp2[n];
        wv[384] = s + bp2[0];
    }
}

// 64 rows/block, 4 lanes/row (32 cols each). svec[j*SVPAD + r].
__global__ __launch_bounds__(256) void head_svec(const float* __restrict__ x,
                                                 const float* __restrict__ rsd,
                                                 const float* __restrict__ wv,
                                                 float* __restrict__ svec) {
    __shared__ float wvL[384];
    const int tid = threadIdx.x;
    if (tid < 128) {
        wvL[tid]       = wv[tid];
        wvL[tid + 128] = wv[tid + 128];
        wvL[tid + 256] = wv[tid + 256];
    }
    __syncthreads();
    const int sub = tid & 3;
    const int r = blockIdx.x * 64 + (tid >> 2);
    if (r >= N_TOT) return;
    const float* xp = x + (size_t)r * E_DIM + sub * 32;
    float xr[32];
#pragma unroll
    for (int i = 0; i < 8; i++) {
        float4 v = *(const float4*)(xp + i * 4);
        xr[i * 4 + 0] = v.x; xr[i * 4 + 1] = v.y;
        xr[i * 4 + 2] = v.z; xr[i * 4 + 3] = v.w;
    }
    const float sc = rsd[r];
#pragma unroll
    for (int j = 0; j < 3; j++) {
        const float* wp = &wvL[j * 128 + sub * 32];
        float p = 0.f;
#pragma unroll
        for (int i = 0; i < 32; i++) p += xr[i] * wp[i];
        p += __shfl_xor(p, 1, 64);
        p += __shfl_xor(p, 2, 64);
        if (sub == 0) svec[j * SVPAD + r] = sc * p;
    }
}

// One thread per triple: 3 gathers from the 28 KB-per-segment svec tables.
__global__ __launch_bounds__(256) void head_final(const float* __restrict__ svec,
                                                  const int* __restrict__ tpl,
                                                  const float* __restrict__ wv,
                                                  float* __restrict__ outp) {
    int m = blockIdx.x * 256 + threadIdx.x;
    if (m >= M_TPL) return;
    int d1 = tpl[3 * m + 0];
    int d2 = tpl[3 * m + 1];
    int se = tpl[3 * m + 2];
    float c0 = wv[384];
    outp[m] = hshrink(svec[d1] + svec[SVPAD + d2] + svec[2 * SVPAD + se] + c0);
}

// ---------------------------------------------------------------------------
extern "C" void kernel_launch(void* const* d_in, const int* in_sizes, int n_in,
                              void* d_out, int out_size, void* d_ws, size_t ws_size,
                              hipStream_t stream) {
    const float* drugF = (const float*)d_in[0];
    const float* A     = (const float*)d_in[1];
    const int*   tpl   = (const int*)d_in[2];
    const float* rsd   = (const float*)d_in[3];
    const float* W1    = (const float*)d_in[4];
    const float* b1    = (const float*)d_in[5];
    const float* W2    = (const float*)d_in[6];
    const float* b2    = (const float*)d_in[7];
    const float* embSe = (const float*)d_in[8];
    const float* Wl    = (const float*)d_in[9];
    const float* bl    = (const float*)d_in[10];
    const float* Wp1   = (const float*)d_in[11];
    const float* bp1   = (const float*)d_in[12];
    const float* Wp2   = (const float*)d_in[13];
    const float* bp2   = (const float*)d_in[14];
    float* outp = (float*)d_out;

    float* ws = (float*)d_ws;
    const size_t XSZ = (size_t)N_TOT * E_DIM;   // 896000 floats
    const size_t P_AX  = (size_t)SPL_AX * XSZ;
    const size_t P_MLP = (size_t)SPL_MLP * N_D * E_DIM;
    const size_t PARTS = P_AX > P_MLP ? P_AX : P_MLP;
    float* x     = ws;
    float* parts = ws + XSZ;
    u16* xT   = (u16*)(ws + XSZ + PARTS);
    u16* W1T  = xT + (size_t)128 * KPAD;
    float* wv   = (float*)(W1T + (size_t)128 * 1024);   // 385 floats (pad 512)
    float* svec = wv + 512;                              // 3 * SVPAD floats
    u16* Atl  = (u16*)(svec + 3 * SVPAD);                // 110*56*64*128 bf16

    // 0) W1 -> bf16 transpose + head weight-vector precompute + A repack
    transpose_bf16<<<dim3(1024 / 64, 2), 256, 0, stream>>>(W1, W1T, F_SIZE, 1024);
    head_wvec<<<dim3(1), 256, 0, stream>>>(Wp1, Wp2, bp1, bp2, wv);
    repack_a<<<dim3(NXT * 64), 256, 0, stream>>>(A, Atl);
    // 1) MLP layer 1 (r9 pipelined DMA split-K) + fused-reduce MLP layer 2
    gemm_dma<<<dim3((N_D + 63) / 64, SPL_MLP), 256, 0, stream>>>(
        drugF, F_SIZE, W1T, 1024, parts, N_D, F_SIZE);
    gemm_small2<<<dim3((N_D + 15) / 16), 256, 0, stream>>>(
        parts, SPL_MLP, (size_t)N_D * E_DIM, b1, W2, b2, x, N_D, 0);
    // 2) embSe rows
    emb_copy<<<dim3((N_SE * E_DIM / 4 + 255) / 256), 256, 0, stream>>>(embSe, x);
    // 3) two propagation layers over the tiled A (DRAM-linear reads)
    for (int l = 0; l < 2; l++) {
        transpose_bf16<<<dim3(KPAD / 64, 2), 256, 0, stream>>>(x, xT, N_TOT, KPAD);
        gemm_tiled<<<dim3(NXT, SPL_AX), 256, 0, stream>>>(
            Atl, xT, parts, N_TOT);
        gemm_small2<<<dim3((N_TOT + 15) / 16), 256, 0, stream>>>(
            parts, SPL_AX, XSZ, nullptr,
            Wl + (size_t)l * E_DIM * E_DIM, bl + (size_t)l * E_DIM, x, N_TOT, 1);
    }
    // 4) head: per-row scalar tables, then 3-gather + hardshrink
    head_svec<<<dim3((N_TOT + 63) / 64), 256, 0, stream>>>(x, rsd, wv, svec);
    head_final<<<dim3((M_TPL + 255) / 256), 256, 0, stream>>>(svec, tpl, wv, outp);
}

// Round 13
// 480.830 us; speedup vs baseline: 1.1581x; 1.1581x over previous
//
#include <hip/hip_runtime.h>
#include <hip/hip_bf16.h>

// Problem constants (from reference setup_inputs)
#define F_SIZE 1024
#define E_DIM  128
#define N_D    6000
#define N_SE   1000
#define N_TOT  7000
#define M_TPL  300000
#define LAMB   1e-6f
#define KPAD   7040   // N_TOT rounded up (xT leading dim)
#define SPL_AX  9     // split-K for A@x: 110 x-tiles * 9 = 990 blocks (r9-proven)
#define SPL_MLP 8     // split-K for MLP1: 94 * 8 = 752 blocks
#define SVPAD  7168   // svec row stride

typedef __bf16 bf16x8 __attribute__((ext_vector_type(8)));
typedef float  f32x4  __attribute__((ext_vector_type(4)));
typedef unsigned short u16;

__device__ __forceinline__ float hshrink(float v) {
    return fabsf(v) > LAMB ? v : 0.0f;
}

// RNE float -> bf16 bits (inputs are finite; no NaN handling needed)
__device__ __forceinline__ u16 f2bf(float f) {
    unsigned int u = __builtin_bit_cast(unsigned int, f);
    unsigned int r = u + 0x7fffu + ((u >> 16) & 1u);
    return (u16)(r >> 16);
}

// Async global->LDS DMA, 16B per lane. LDS dest wave-uniform + lane*16.
__device__ __forceinline__ void gl_lds16(const void* g, void* l) {
    __builtin_amdgcn_global_load_lds(
        (__attribute__((address_space(1))) void*)(void*)(g),
        (__attribute__((address_space(3))) void*)(l), 16, 0, 0);
}

// ---------------------------------------------------------------------------
// r9's proven GEMM: fp32 A LDS-DMA staged, BK=32, 2-deep dbuf, counted
// vmcnt(4) (never 0 in the pipelined loop). Empirical floor for the A@x
// access pattern (~109 us/layer); six structural theories falsified
// (schedule x3, bytes, contiguity, pipeline depth, B-redundancy, linearity).
// ---------------------------------------------------------------------------
__global__ __launch_bounds__(256) void gemm_dma(const float* __restrict__ A, int lda,
                                                const u16* __restrict__ BT, int ldbt,
                                                float* __restrict__ Cpart,
                                                int M, int K) {
    __shared__ float As[2][64 * 32];    // 2 x 8 KB
    __shared__ u16   Bs[2][128 * 32];   // 2 x 8 KB
    const int tid  = threadIdx.x;
    const int lane = tid & 63;
    const int w    = tid >> 6;
    const int fm   = lane & 15;
    const int quad = lane >> 4;
    const int wm   = (w & 1) * 32;
    const int wn   = (w >> 1) * 64;
    const int row0 = blockIdx.x * 64;
    const int sp = blockIdx.y, nsp = gridDim.y;
    const int KT  = (K + 31) / 32;
    const int kt0 = sp * KT / nsp;
    const int kt1 = (sp + 1) * KT / nsp;
    const int ktFall = K >> 5;
    const int ktF = kt1 < ktFall ? kt1 : ktFall;

    int aLoc[2], aQ[2];
    const float* aG[2];
#pragma unroll
    for (int j = 0; j < 2; j++) {
        int r = w * 16 + j * 8 + (lane >> 3);
        aLoc[j] = r;
        int grow = row0 + r; if (grow > M - 1) grow = M - 1;
        aQ[j] = (lane & 7) ^ (r & 7);
        aG[j] = A + (size_t)grow * lda + aQ[j] * 4;
    }
    const u16* bG[2];
#pragma unroll
    for (int j = 0; j < 2; j++) {
        int n = w * 32 + j * 16 + (lane >> 2);
        int q = (lane & 3) ^ ((n >> 1) & 3);
        bG[j] = BT + (size_t)n * ldbt + q * 8;
    }

    const f32x4 zero = {0.f, 0.f, 0.f, 0.f};
    f32x4 acc[2][4];
#pragma unroll
    for (int i = 0; i < 2; i++)
#pragma unroll
        for (int j = 0; j < 4; j++) acc[i][j] = zero;

#define STAGE_T(buf, kt)                                                      \
    {                                                                         \
        const int k0s = (kt) * 32;                                            \
        _Pragma("unroll") for (int j = 0; j < 2; j++)                         \
            gl_lds16(aG[j] + k0s, &As[buf][(w * 16 + j * 8) * 32]);           \
        _Pragma("unroll") for (int j = 0; j < 2; j++)                         \
            gl_lds16(bG[j] + k0s, &Bs[buf][(w * 32 + j * 16) * 32]);          \
    }

#define COMPUTE_T(buf)                                                        \
    {                                                                         \
        bf16x8 bfr[4];                                                        \
        _Pragma("unroll") for (int ni = 0; ni < 4; ni++) {                    \
            int n = wn + ni * 16 + fm;                                        \
            bfr[ni] = *(const bf16x8*)&Bs[buf][n * 32 +                       \
                                              (quad ^ ((n >> 1) & 3)) * 8];   \
        }                                                                     \
        _Pragma("unroll") for (int mi = 0; mi < 2; mi++) {                    \
            int r = wm + mi * 16 + fm;                                        \
            int s = r & 7;                                                    \
            f32x4 f0 = *(const f32x4*)&As[buf][r * 32 + ((quad * 2) ^ s) * 4];\
            f32x4 f1 = *(const f32x4*)&As[buf][r * 32 +                       \
                                              ((quad * 2 + 1) ^ s) * 4];      \
            u16 us[8];                                                        \
            us[0] = f2bf(f0[0]); us[1] = f2bf(f0[1]);                         \
            us[2] = f2bf(f0[2]); us[3] = f2bf(f0[3]);                         \
            us[4] = f2bf(f1[0]); us[5] = f2bf(f1[1]);                         \
            us[6] = f2bf(f1[2]); us[7] = f2bf(f1[3]);                         \
            bf16x8 af = *(bf16x8*)us;                                         \
            _Pragma("unroll") for (int ni = 0; ni < 4; ni++)                  \
                acc[mi][ni] = __builtin_amdgcn_mfma_f32_16x16x32_bf16(        \
                    af, bfr[ni], acc[mi][ni], 0, 0, 0);                       \
        }                                                                     \
    }

    if (ktF > kt0) {
        STAGE_T(0, kt0);
        for (int t = kt0; t < ktF; t++) {
            const int cur = (t - kt0) & 1;
            if (t + 1 < ktF) {
                STAGE_T(cur ^ 1, t + 1);
                asm volatile("s_waitcnt vmcnt(4)" ::: "memory");
            } else {
                asm volatile("s_waitcnt vmcnt(0)" ::: "memory");
            }
            __builtin_amdgcn_s_barrier();
            COMPUTE_T(cur);
            __builtin_amdgcn_s_barrier();
        }
    }
    // Masked tail tile (only the last split, K%32 != 0) — un-pipelined.
    for (int kt = ktF; kt < kt1; kt++) {
        const int k0 = kt * 32;
        __syncthreads();
#pragma unroll
        for (int j = 0; j < 2; j++) {
            float4 v = make_float4(0.f, 0.f, 0.f, 0.f);
            if (k0 + aQ[j] * 4 + 4 <= K) v = *(const float4*)(aG[j] + k0);
            *(float4*)&As[0][aLoc[j] * 32 + (lane & 7) * 4] = v;
        }
#pragma unroll
        for (int j = 0; j < 2; j++)
            gl_lds16(bG[j] + k0, &Bs[0][(w * 32 + j * 16) * 32]);
        __syncthreads();
        COMPUTE_T(0);
    }
#undef STAGE_T
#undef COMPUTE_T

    float* op = Cpart + (size_t)sp * M * E_DIM;
#pragma unroll
    for (int mi = 0; mi < 2; mi++) {
#pragma unroll
        for (int rr = 0; rr < 4; rr++) {
            int row = row0 + wm + mi * 16 + quad * 4 + rr;
            if (row < M) {
#pragma unroll
                for (int ni = 0; ni < 4; ni++)
                    op[(size_t)row * E_DIM + wn + ni * 16 + fm] = acc[mi][ni][rr];
            }
        }
    }
}

// ---------------------------------------------------------------------------
// Small GEMM (K=128), BM=16: fuses (a) the split-K reduction of its fp32 A
// input, (b) bias+act, (c) OPTIONAL bf16 transpose write (xT columns for the
// next layer's B operand), (d) OPTIONAL head svec computation:
//   svec[j][r] = rsd[r] * (out_row[r] . wv_j)     (j = 0,1,2)
// ---------------------------------------------------------------------------
__global__ __launch_bounds__(256) void gemm_small2(const float* __restrict__ parts,
                                                   int nparts, size_t partStride,
                                                   const float* __restrict__ preBias,
                                                   const float* __restrict__ W,
                                                   const float* __restrict__ bias,
                                                   float* __restrict__ outp,
                                                   int Mrows, int act,
                                                   u16* __restrict__ xTout, int ldxt,
                                                   const float* __restrict__ wvg,
                                                   const float* __restrict__ rsd,
                                                   float* __restrict__ svecOut) {
    __shared__ float Asum[16][132];
    __shared__ u16   tbuf[16][128];
    __shared__ float wvL[384];
    const int tid = threadIdx.x;
    const int row0 = blockIdx.x * 16;
    const int r  = tid >> 4;
    const int kc = (tid & 15) * 8;
    const int grow = row0 + r;

    if (svecOut != nullptr && tid < 128) {
        wvL[tid]       = wvg[tid];
        wvL[tid + 128] = wvg[tid + 128];
        wvL[tid + 256] = wvg[tid + 256];
    }

    float4 s0 = make_float4(0.f, 0.f, 0.f, 0.f);
    float4 s1 = make_float4(0.f, 0.f, 0.f, 0.f);
    if (grow < Mrows) {
        for (int s = 0; s < nparts; s++) {
            const float* p = parts + (size_t)s * partStride + (size_t)grow * 128 + kc;
            float4 q0 = *(const float4*)p;
            float4 q1 = *(const float4*)(p + 4);
            s0.x += q0.x; s0.y += q0.y; s0.z += q0.z; s0.w += q0.w;
            s1.x += q1.x; s1.y += q1.y; s1.z += q1.z; s1.w += q1.w;
        }
        if (preBias != nullptr) {
            float4 pb0 = *(const float4*)(preBias + kc);
            float4 pb1 = *(const float4*)(preBias + kc + 4);
            s0.x = fmaxf(s0.x + pb0.x, 0.f); s0.y = fmaxf(s0.y + pb0.y, 0.f);
            s0.z = fmaxf(s0.z + pb0.z, 0.f); s0.w = fmaxf(s0.w + pb0.w, 0.f);
            s1.x = fmaxf(s1.x + pb1.x, 0.f); s1.y = fmaxf(s1.y + pb1.y, 0.f);
            s1.z = fmaxf(s1.z + pb1.z, 0.f); s1.w = fmaxf(s1.w + pb1.w, 0.f);
        }
    }
    *(float4*)&Asum[r][kc]     = s0;
    *(float4*)&Asum[r][kc + 4] = s1;
    __syncthreads();

    float acc[8];
#pragma unroll
    for (int j = 0; j < 8; j++) acc[j] = 0.f;
    const float* wp = W + kc;
#pragma unroll 4
    for (int k = 0; k < 128; k++) {
        float a = Asum[r][k];
        float4 w0 = *(const float4*)(wp + (size_t)k * 128);
        float4 w1 = *(const float4*)(wp + (size_t)k * 128 + 4);
        acc[0] += a * w0.x; acc[1] += a * w0.y;
        acc[2] += a * w0.z; acc[3] += a * w0.w;
        acc[4] += a * w1.x; acc[5] += a * w1.y;
        acc[6] += a * w1.z; acc[7] += a * w1.w;
    }

    float v[8];
    u16 us[8];
    if (grow < Mrows) {
        float4 bv0 = *(const float4*)(bias + kc);
        float4 bv1 = *(const float4*)(bias + kc + 4);
        v[0] = acc[0] + bv0.x; v[1] = acc[1] + bv0.y;
        v[2] = acc[2] + bv0.z; v[3] = acc[3] + bv0.w;
        v[4] = acc[4] + bv1.x; v[5] = acc[5] + bv1.y;
        v[6] = acc[6] + bv1.z; v[7] = acc[7] + bv1.w;
#pragma unroll
        for (int j = 0; j < 8; j++)
            v[j] = (act == 0) ? fmaxf(v[j], 0.f) : hshrink(v[j]);
        float* op = outp + (size_t)grow * 128 + kc;
        *(float4*)op       = make_float4(v[0], v[1], v[2], v[3]);
        *(float4*)(op + 4) = make_float4(v[4], v[5], v[6], v[7]);
#pragma unroll
        for (int j = 0; j < 8; j++) us[j] = f2bf(v[j]);
    } else {
#pragma unroll
        for (int j = 0; j < 8; j++) { v[j] = 0.f; us[j] = 0; }
    }
    *(uint4*)&tbuf[r][kc] = *(uint4*)us;      // all threads (zeros when OOB)

    // Head svec (final layer only): 3 dots vs wv, 16-lane reduce, scale rsd.
    if (svecOut != nullptr && grow < Mrows) {
        const float sc = rsd[grow];
#pragma unroll
        for (int j = 0; j < 3; j++) {
            const float* wj = &wvL[j * 128 + kc];
            float p = v[0] * wj[0] + v[1] * wj[1] + v[2] * wj[2] + v[3] * wj[3]
                    + v[4] * wj[4] + v[5] * wj[5] + v[6] * wj[6] + v[7] * wj[7];
            p += __shfl_xor(p, 1, 16);
            p += __shfl_xor(p, 2, 16);
            p += __shfl_xor(p, 4, 16);
            p += __shfl_xor(p, 8, 16);
            if ((tid & 15) == 0) svecOut[j * SVPAD + grow] = sc * p;
        }
    }

    // Transposed bf16 write: xT[c][row0..row0+16) from tbuf columns.
    if (xTout != nullptr) {
        __syncthreads();
        const int c = tid >> 1;
        const int h = tid & 1;
        u16 o[8];
#pragma unroll
        for (int i = 0; i < 8; i++) o[i] = tbuf[h * 8 + i][c];
        *(uint4*)(xTout + (size_t)c * ldxt + row0 + h * 8) = *(uint4*)o;
    }
}

// ---------------------------------------------------------------------------
// src [nrows][128] fp32 -> dst [128][kpad] bf16 (cols >= nrows zero-filled)
// grid: (ceil(rows64)/64, 2). Used for W1T and the embSe slice of xT.
// ---------------------------------------------------------------------------
__global__ __launch_bounds__(256) void transpose_bf16(const float* __restrict__ src,
                                                      u16* __restrict__ dst,
                                                      int nrows, int kpad) {
    __shared__ float t[64][65];
    const int r0 = blockIdx.x * 64;
    const int c0 = blockIdx.y * 64;
    const int tid = threadIdx.x;
    {
        const int i  = tid >> 4;
        const int cq = (tid & 15) * 4;
#pragma unroll
        for (int j = 0; j < 4; j++) {
            int r = r0 + i + j * 16;
            float4 v = make_float4(0.f, 0.f, 0.f, 0.f);
            if (r < nrows) v = *(const float4*)(src + (size_t)r * E_DIM + c0 + cq);
            t[i + j * 16][cq + 0] = v.x;
            t[i + j * 16][cq + 1] = v.y;
            t[i + j * 16][cq + 2] = v.z;
            t[i + j * 16][cq + 3] = v.w;
        }
    }
    __syncthreads();
    {
        const int ci = tid >> 2;
        const int rq = (tid & 3) * 16;
        u16 us[16];
#pragma unroll
        for (int j = 0; j < 16; j++) us[j] = f2bf(t[rq + j][ci]);
        u16* dp = dst + (size_t)(c0 + ci) * kpad + r0 + rq;
        *(uint4*)dp       = *(uint4*)&us[0];
        *(uint4*)(dp + 8) = *(uint4*)&us[8];
    }
}

// Zero xT cols [7024, 7040) (beyond what the embSe transpose covers).
__global__ void zpad_xt(u16* __restrict__ xT) {
    const int c = threadIdx.x >> 1;
    const int h = threadIdx.x & 1;
    u16 z[8] = {0, 0, 0, 0, 0, 0, 0, 0};
    *(uint4*)(xT + (size_t)c * KPAD + 7024 + h * 8) = *(uint4*)z;
}

// ---------------------------------------------------------------------------
// Head algebra (inner hardshrink ~= identity at lambda=1e-6):
//   out[m] = HS( s0[d1] + s1[d2] + s2[se] + c0 )
//   wv_j = Wp1[j*128:(j+1)*128] @ Wp2,  c0 = bp1.Wp2 + bp2
// ---------------------------------------------------------------------------
__global__ __launch_bounds__(256) void head_wvec(const float* __restrict__ Wp1,
                                                 const float* __restrict__ Wp2,
                                                 const float* __restrict__ bp1,
                                                 const float* __restrict__ bp2,
                                                 float* __restrict__ wv) {
    const int tid = threadIdx.x;
#pragma unroll
    for (int rr = 0; rr < 2; rr++) {
        int row = tid + rr * 256;
        if (row < 384) {
            const float* wp = Wp1 + (size_t)row * 128;
            float s = 0.f;
            for (int n = 0; n < 128; n += 4) {
                float4 a = *(const float4*)(wp + n);
                float4 b = *(const float4*)(Wp2 + n);
                s += a.x * b.x + a.y * b.y + a.z * b.z + a.w * b.w;
            }
            wv[row] = s;
        }
    }
    if (tid == 0) {
        float s = 0.f;
        for (int n = 0; n < 128; n++) s += bp1[n] * Wp2[n];
        wv[384] = s + bp2[0];
    }
}

// One thread per triple: 3 gathers from the 28 KB-per-segment svec tables.
__global__ __launch_bounds__(256) void head_final(const float* __restrict__ svec,
                                                  const int* __restrict__ tpl,
                                                  const float* __restrict__ wv,
                                                  float* __restrict__ outp) {
    int m = blockIdx.x * 256 + threadIdx.x;
    if (m >= M_TPL) return;
    int d1 = tpl[3 * m + 0];
    int d2 = tpl[3 * m + 1];
    int se = tpl[3 * m + 2];
    float c0 = wv[384];
    outp[m] = hshrink(svec[d1] + svec[SVPAD + d2] + svec[2 * SVPAD + se] + c0);
}

// ---------------------------------------------------------------------------
extern "C" void kernel_launch(void* const* d_in, const int* in_sizes, int n_in,
                              void* d_out, int out_size, void* d_ws, size_t ws_size,
                              hipStream_t stream) {
    const float* drugF = (const float*)d_in[0];
    const float* A     = (const float*)d_in[1];
    const int*   tpl   = (const int*)d_in[2];
    const float* rsd   = (const float*)d_in[3];
    const float* W1    = (const float*)d_in[4];
    const float* b1    = (const float*)d_in[5];
    const float* W2    = (const float*)d_in[6];
    const float* b2    = (const float*)d_in[7];
    const float* embSe = (const float*)d_in[8];
    const float* Wl    = (const float*)d_in[9];
    const float* bl    = (const float*)d_in[10];
    const float* Wp1   = (const float*)d_in[11];
    const float* bp1   = (const float*)d_in[12];
    const float* Wp2   = (const float*)d_in[13];
    const float* bp2   = (const float*)d_in[14];
    float* outp = (float*)d_out;

    float* ws = (float*)d_ws;
    const size_t XSZ = (size_t)N_TOT * E_DIM;   // 896000 floats
    const size_t P_AX  = (size_t)SPL_AX * XSZ;
    const size_t P_MLP = (size_t)SPL_MLP * N_D * E_DIM;
    const size_t PARTS = P_AX > P_MLP ? P_AX : P_MLP;
    float* x     = ws;
    float* parts = ws + XSZ;
    u16* xT   = (u16*)(ws + XSZ + PARTS);
    u16* W1T  = xT + (size_t)128 * KPAD;
    float* wv   = (float*)(W1T + (size_t)128 * 1024);   // 385 floats (pad 512)
    float* svec = wv + 512;                              // 3 * SVPAD floats

    // 0) W1 -> bf16 transpose, head wv, embSe -> xT cols [6000,7024), zpad
    transpose_bf16<<<dim3(1024 / 64, 2), 256, 0, stream>>>(W1, W1T, F_SIZE, 1024);
    head_wvec<<<dim3(1), 256, 0, stream>>>(Wp1, Wp2, bp1, bp2, wv);
    transpose_bf16<<<dim3(16, 2), 256, 0, stream>>>(embSe, xT + 6000, N_SE, KPAD);
    zpad_xt<<<dim3(1), 256, 0, stream>>>(xT);
    // 1) MLP layer 1 (r9 pipelined DMA split-K) + fused-reduce MLP layer 2
    //    (epilogue writes x rows [0,6000) AND their xT columns)
    gemm_dma<<<dim3((N_D + 63) / 64, SPL_MLP), 256, 0, stream>>>(
        drugF, F_SIZE, W1T, 1024, parts, N_D, F_SIZE);
    gemm_small2<<<dim3((N_D + 15) / 16), 256, 0, stream>>>(
        parts, SPL_MLP, (size_t)N_D * E_DIM, b1, W2, b2, x, N_D, 0,
        xT, KPAD, nullptr, nullptr, nullptr);
    // 2) two propagation layers: x = HS( (A@x) @ Wl[i] + bl[i] )
    //    layer 0 epilogue: fused xT write; layer 1 epilogue: fused head svec
    for (int l = 0; l < 2; l++) {
        gemm_dma<<<dim3((N_TOT + 63) / 64, SPL_AX), 256, 0, stream>>>(
            A, N_TOT, xT, KPAD, parts, N_TOT, N_TOT);
        gemm_small2<<<dim3((N_TOT + 15) / 16), 256, 0, stream>>>(
            parts, SPL_AX, XSZ, nullptr,
            Wl + (size_t)l * E_DIM * E_DIM, bl + (size_t)l * E_DIM, x, N_TOT, 1,
            (l == 0) ? xT : nullptr, KPAD,
            (l == 1) ? wv : nullptr, (l == 1) ? rsd : nullptr,
            (l == 1) ? svec : nullptr);
    }
    // 3) head: 3-gather + hardshrink from the fused svec tables
    head_final<<<dim3((M_TPL + 255) / 256), 256, 0, stream>>>(svec, tpl, wv, outp);
}